// Round 2
// baseline (378.407 us; speedup 1.0000x reference)
//
#include <hip/hip_runtime.h>
#include <stdint.h>

typedef unsigned short u16;
typedef short short8 __attribute__((ext_vector_type(8)));
typedef float floatx4 __attribute__((ext_vector_type(4)));

#define NPERB   40000
#define NPTS    80000
#define KNBR    16
#define CIN     64
#define MDIM    16
#define CADD    3
#define CF      (CIN + CADD)
#define COUT    128
#define KF      1072
#define KP      1088
#define NKT     34        // KP/32 K-steps
#define PTSB    16        // fused-fallback: points per block
#define SLAB    65        // fused-fallback: chunks per kt slab
#define GR      64        // gemm: rows per block
#define PPB     8         // pconv: points per block (4 waves x 2)

__device__ __forceinline__ u16 f2bf(float f) {
    union { float f; unsigned int u; } v; v.f = f;
    unsigned int u = v.u;
    return (u16)((u + 0x7FFFu + ((u >> 16) & 1u)) >> 16);
}
__device__ __forceinline__ short8 pack8(floatx4 x, floatx4 y) {
    union { short8 v; u16 a[8]; } u;
    u.a[0] = f2bf(x[0]); u.a[1] = f2bf(x[1]); u.a[2] = f2bf(x[2]); u.a[3] = f2bf(x[3]);
    u.a[4] = f2bf(y[0]); u.a[5] = f2bf(y[1]); u.a[6] = f2bf(y[2]); u.a[7] = f2bf(y[3]);
    return u.v;
}
// fused-fallback swizzle (16B-chunk XOR)
__device__ __forceinline__ unsigned swz(unsigned chunk) {
    return chunk ^ ((chunk >> 3) & 7u);
}
// gemm A-tile swizzle: involution on 16B-chunk index (bits0-1 ^= bits4-5).
// Read pattern (rows vary, chunk-col fixed) then spans all 8 bank-quads
// with 2 lanes each -> conflict-free (2-way is free, m136).
__device__ __forceinline__ unsigned aswz(unsigned c) {
    return c ^ ((c >> 4) & 3u);
}
// async global -> LDS, 16B per lane; LDS dest = uniform base + lane*16 (linear).
__device__ __forceinline__ void gload_lds16(const void* g, void* l) {
    __builtin_amdgcn_global_load_lds(
        (const __attribute__((address_space(1))) void*)g,
        (__attribute__((address_space(3))) void*)l, 16, 0, 0);
}

// Convert+pad linear_weight fp32 [128,1072] -> bf16 ws [128,1088] (zero pad).
__global__ void prep_lw_kernel(const float* __restrict__ lw, u16* __restrict__ lwp) {
    int i = blockIdx.x * 256 + threadIdx.x;
    if (i >= COUT * KP) return;
    int o = i / KP, f = i - o * KP;
    lwp[i] = (f < KF) ? f2bf(lw[(size_t)o * KF + f]) : (u16)0;
}

// ============================ SPLIT PATH ============================
// Kernel 1: pconv. One wave handles 2 points; writes row-major bf16
// pconv[p][f] (f = c*16+m, padded to 1088 with zeros) to workspace.
// No barriers, contiguous 2KB/point stores, ~8KB LDS -> high occupancy
// and shallow dependency chains (one vmcnt epoch per 2 points).
__device__ __forceinline__ void emit_point(
    int lane, float av, const float (&fv)[KNBR], const float* wl,
    u16* __restrict__ dst)
{
    const int em = lane & 15, ec = lane >> 4;
    // extra channels 64..66 (67 = zero pad): f = 1024 + ec*16 + em = 1024+lane
    float ev = 0.f;
#pragma unroll
    for (int k = 0; k < KNBR; k++)
        ev += __shfl(av, k * CADD + ec) * wl[k * MDIM + em];
    if (ec == 3) ev = 0.f;                       // channel 67 + f>=1072 pad
    dst[1024 + lane] = f2bf(ev);                 // 128B contiguous per wave

    // main channels: lane = c (0..63), f = c*16 + m
    floatx4 a0 = 0, a1 = 0, a2 = 0, a3 = 0;
#pragma unroll
    for (int k = 0; k < KNBR; k++) {
        const floatx4* w4 = (const floatx4*)(wl + k * MDIM);  // uniform -> bcast
        const float fvk = fv[k];
        a0 += fvk * w4[0]; a1 += fvk * w4[1];
        a2 += fvk * w4[2]; a3 += fvk * w4[3];
    }
    *(short8*)(dst + lane * 16)     = pack8(a0, a1);   // m 0..7
    *(short8*)(dst + lane * 16 + 8) = pack8(a2, a3);   // m 8..15
}

__global__ __launch_bounds__(256) void pconv_kernel(
    const float* __restrict__ inp,   // [2,40000,64] fp32
    const int*   __restrict__ nbr,   // [2,40000,16] int32
    const float* __restrict__ wn,    // [2,40000,16,16] fp32
    const float* __restrict__ addl,  // [2,40000,16,3] fp32
    u16* __restrict__ pc)            // [80000,1088] bf16
{
    __shared__ __align__(16) float Wns[PPB * KNBR * MDIM];   // 8KB

    const int wave = threadIdx.x >> 6;
    const int lane = threadIdx.x & 63;
    const int pbase = blockIdx.x * PPB;         // 40000 % 8 == 0
    const float* inpb = inp + ((pbase >= NPERB) ? (size_t)NPERB * CIN : 0);

    const int pr0 = wave * 2;
    const int p0  = __builtin_amdgcn_readfirstlane(pbase + pr0);
    const int p1  = p0 + 1;

    float* wl0 = Wns + pr0 * (KNBR * MDIM);
    float* wl1 = wl0 + KNBR * MDIM;
    gload_lds16(wn + (size_t)p0 * (KNBR * MDIM) + lane * 4, wl0);
    gload_lds16(wn + (size_t)p1 * (KNBR * MDIM) + lane * 4, wl1);

    float av0 = (lane < KNBR * CADD) ? addl[(size_t)p0 * (KNBR * CADD) + lane] : 0.f;
    float av1 = (lane < KNBR * CADD) ? addl[(size_t)p1 * (KNBR * CADD) + lane] : 0.f;

    const int* nb0 = nbr + (size_t)p0 * KNBR;   // uniform -> s_loads
    const int* nb1 = nbr + (size_t)p1 * KNBR;
    int idx0[KNBR], idx1[KNBR];
#pragma unroll
    for (int k = 0; k < KNBR; k++) idx0[k] = nb0[k];
#pragma unroll
    for (int k = 0; k < KNBR; k++) idx1[k] = nb1[k];

    float fv0[KNBR], fv1[KNBR];
#pragma unroll
    for (int k = 0; k < KNBR; k++) fv0[k] = inpb[(size_t)idx0[k] * CIN + lane];
#pragma unroll
    for (int k = 0; k < KNBR; k++) fv1[k] = inpb[(size_t)idx1[k] * CIN + lane];

    asm volatile("s_waitcnt vmcnt(0)" ::: "memory");  // wn staging + gathers
    __builtin_amdgcn_sched_barrier(0);

    emit_point(lane, av0, fv0, wl0, pc + (size_t)p0 * KP);
    emit_point(lane, av1, fv1, wl1, pc + (size_t)p1 * KP);
}

// Kernel 2: GEMM [80000 x 1088]bf16 x [1088 x 128]bf16 -> fp32 (+bias).
// Block = 64 rows x 128 cols, 8 waves: wave tile 16 rows (rt=wave&3) x
// 64 cols (c0=(wave>>2)*64). A staged global->LDS (double-buffered,
// aswz-swizzled via pre-swizzled SOURCE address, LDS dest linear - m104).
// B = lwp stays L2-hot (278KB). Per-wave stores are 4x64B = 256B/row
// contiguous -> no write amplification (r1 lesson).
__global__ __launch_bounds__(512) void gemm_kernel(
    const u16* __restrict__ pc,     // [80000,1088] bf16
    const u16* __restrict__ lwp,    // [128,1088] bf16
    const float* __restrict__ bias, // [128] fp32
    float* __restrict__ out)        // [80000,128] fp32
{
    __shared__ __align__(16) u16 At[2][GR * 32];   // 2 x 4KB

    const int wave = threadIdx.x >> 6;
    const int lane = threadIdx.x & 63;
    const int pbase = blockIdx.x * GR;             // 40000 % 64 == 0
    const int r16 = lane & 15, quad = lane >> 4;
    const int rt = wave & 3;
    const int c0 = (wave >> 2) * 64;

    // staging source (waves 0..3, one gload_lds each per kt):
    // LDS slot s = wave*64+lane holds chunk c = aswz(s) (involution).
    const u16* ssrc = nullptr;
    if (wave < 4) {
        unsigned s = (unsigned)wave * 64 + lane;
        unsigned c = aswz(s);
        ssrc = pc + (size_t)(pbase + (c >> 2)) * KP + (c & 3u) * 8;
    }
    u16* sdst0 = &At[0][(size_t)wave * 64 * 8];
    u16* sdst1 = &At[1][(size_t)wave * 64 * 8];

    // A-fragment: row rt*16+r16, chunk-col quad -> swizzled slot
    const unsigned ca = (unsigned)(rt * 16 + r16) * 4 + quad;
    const unsigned slot = aswz(ca);

    // B pointers: lwp[o][k], o = c0 + n*16 + r16, k = kt*32 + quad*8
    const u16* B0 = lwp + (size_t)(c0 + r16) * KP + quad * 8;
    const u16* B1 = B0 + (size_t)16 * KP;
    const u16* B2 = B0 + (size_t)32 * KP;
    const u16* B3 = B0 + (size_t)48 * KP;
    const float bv0 = bias[c0 + r16];
    const float bv1 = bias[c0 + 16 + r16];
    const float bv2 = bias[c0 + 32 + r16];
    const float bv3 = bias[c0 + 48 + r16];

    // prologue: stage kt=0 into buf0
    if (wave < 4) gload_lds16(ssrc, sdst0);
    asm volatile("s_waitcnt vmcnt(0)" ::: "memory");
    __syncthreads();

    floatx4 acc0 = 0, acc1 = 0, acc2 = 0, acc3 = 0;
    int cur = 0;
    for (int kt = 0; kt < NKT; kt++) {
        // prefetch kt+1 into the other buffer (overlaps with MFMA below)
        if (kt + 1 < NKT && wave < 4)
            gload_lds16(ssrc + (size_t)(kt + 1) * 32, cur ? sdst0 : sdst1);

        short8 A  = *(const short8*)&At[cur][slot * 8];
        short8 b0 = *(const short8*)(B0 + kt * 32);
        short8 b1 = *(const short8*)(B1 + kt * 32);
        short8 b2 = *(const short8*)(B2 + kt * 32);
        short8 b3 = *(const short8*)(B3 + kt * 32);
        acc0 = __builtin_amdgcn_mfma_f32_16x16x32_bf16(A, b0, acc0, 0, 0, 0);
        acc1 = __builtin_amdgcn_mfma_f32_16x16x32_bf16(A, b1, acc1, 0, 0, 0);
        acc2 = __builtin_amdgcn_mfma_f32_16x16x32_bf16(A, b2, acc2, 0, 0, 0);
        acc3 = __builtin_amdgcn_mfma_f32_16x16x32_bf16(A, b3, acc3, 0, 0, 0);

        __syncthreads();    // emits vmcnt(0)+lgkmcnt(0) drain -> staging done
        cur ^= 1;
    }

    // epilogue: D[row=quad*4+r][col=r16]; wave covers 256B/row contiguous
#pragma unroll
    for (int r = 0; r < 4; r++) {
        const size_t row = (size_t)(pbase + rt * 16 + quad * 4 + r) * COUT;
        out[row + c0 + r16]      = acc0[r] + bv0;
        out[row + c0 + 16 + r16] = acc1[r] + bv1;
        out[row + c0 + 32 + r16] = acc2[r] + bv2;
        out[row + c0 + 48 + r16] = acc3[r] + bv3;
    }
}

// ===================== FUSED FALLBACK (r1 kernel) =====================
__device__ __forceinline__ void compute_point(
    int pr, int lane, float av, const float (&fv)[KNBR],
    const float* wl, u16* Apc)
{
    const int em = lane & 15, ec = lane >> 4;
    float ev = 0.f;
#pragma unroll
    for (int k = 0; k < KNBR; k++)
        ev += __shfl(av, k * CADD + ec) * wl[k * MDIM + em];
    if (ec == 3) ev = 0.f;
    {
        unsigned kt   = 32 + (lane >> 5);
        unsigned quad = (lane >> 3) & 3;
        unsigned ch   = kt * SLAB + (unsigned)pr * 4 + quad;
        Apc[swz(ch) * 8 + (lane & 7)] = f2bf(ev);
    }
    floatx4 a0 = 0, a1 = 0, a2 = 0, a3 = 0;
#pragma unroll
    for (int k = 0; k < KNBR; k++) {
        const floatx4* w4 = (const floatx4*)(wl + k * MDIM);
        const float fvk = fv[k];
        a0 += fvk * w4[0]; a1 += fvk * w4[1];
        a2 += fvk * w4[2]; a3 += fvk * w4[3];
    }
    {
        unsigned kt = lane >> 1, qb = (lane & 1) * 2;
        unsigned ch = kt * SLAB + (unsigned)pr * 4 + qb;
        *(short8*)&Apc[swz(ch) * 8]     = pack8(a0, a1);
        *(short8*)&Apc[swz(ch + 1) * 8] = pack8(a2, a3);
    }
}

__global__ __launch_bounds__(512, 6) void fused_kernel(
    const float* __restrict__ inp, const int* __restrict__ nbr,
    const float* __restrict__ wn, const float* __restrict__ addl,
    const u16* __restrict__ lwp, const float* __restrict__ bias,
    float* __restrict__ out)
{
    __shared__ __align__(16) u16   Apc[(NKT * SLAB + 8) * 8];
    __shared__ __align__(16) float Wns[PTSB * KNBR * MDIM];

    const int wave = threadIdx.x >> 6;
    const int lane = threadIdx.x & 63;
    const int pbase = blockIdx.x * PTSB;
    const float* inpb = inp + ((pbase >= NPERB) ? (size_t)NPERB * CIN : 0);

    const int pr0 = wave * 2;
    const int p0  = __builtin_amdgcn_readfirstlane(pbase + pr0);
    const int p1  = p0 + 1;

    float* wl0 = Wns + pr0 * (KNBR * MDIM);
    float* wl1 = wl0 + KNBR * MDIM;
    gload_lds16(wn + (size_t)p0 * (KNBR * MDIM) + lane * 4, wl0);
    gload_lds16(wn + (size_t)p1 * (KNBR * MDIM) + lane * 4, wl1);

    float av0 = (lane < KNBR * CADD) ? addl[(size_t)p0 * (KNBR * CADD) + lane] : 0.f;
    float av1 = (lane < KNBR * CADD) ? addl[(size_t)p1 * (KNBR * CADD) + lane] : 0.f;

    const int* nb0 = nbr + (size_t)p0 * KNBR;
    const int* nb1 = nbr + (size_t)p1 * KNBR;
    int idx0[KNBR], idx1[KNBR];
#pragma unroll
    for (int k = 0; k < KNBR; k++) idx0[k] = nb0[k];
#pragma unroll
    for (int k = 0; k < KNBR; k++) idx1[k] = nb1[k];

    float fv0[KNBR], fv1[KNBR];
#pragma unroll
    for (int k = 0; k < KNBR; k++) fv0[k] = inpb[(size_t)idx0[k] * CIN + lane];
#pragma unroll
    for (int k = 0; k < KNBR; k++) fv1[k] = inpb[(size_t)idx1[k] * CIN + lane];

    asm volatile("s_waitcnt vmcnt(0)" ::: "memory");
    __builtin_amdgcn_sched_barrier(0);

    compute_point(pr0,     lane, av0, fv0, wl0, Apc);
    compute_point(pr0 + 1, lane, av1, fv1, wl1, Apc);

    const int r16 = lane & 15, quad = lane >> 4;
    const int c0 = wave * 16;
    const u16* Bp = lwp + (size_t)(c0 + r16) * KP + quad * 8;
    const unsigned abase = (unsigned)r16 * 4 + quad;
    const float bv = bias[c0 + r16];

    __syncthreads();

    floatx4 acc = 0;
#pragma unroll 2
    for (int kt = 0; kt < NKT; kt++) {
        short8 A = *(const short8*)&Apc[swz((unsigned)kt * SLAB + abase) * 8];
        short8 B = *(const short8*)(Bp + kt * 32);
        acc = __builtin_amdgcn_mfma_f32_16x16x32_bf16(A, B, acc, 0, 0, 0);
    }

#pragma unroll
    for (int r = 0; r < 4; r++) {
        const size_t row = (size_t)(pbase + quad * 4 + r) * COUT;
        out[row + c0 + r16] = acc[r] + bv;
    }
}

// Slow last-resort fallback: all-fp32, one block per point.
__global__ __launch_bounds__(256) void fused_fallback_kernel(
    const float* __restrict__ inp, const int* __restrict__ nbr,
    const float* __restrict__ wn, const float* __restrict__ addl,
    const float* __restrict__ lw, const float* __restrict__ bias,
    float* __restrict__ out)
{
    const int p = blockIdx.x;
    const int b = p / NPERB;
    const int tid = threadIdx.x;
    __shared__ float sf[KNBR * CF];
    __shared__ float sw[KNBR * MDIM];
    __shared__ float sp[KF];

    sw[tid] = wn[(size_t)p * (KNBR * MDIM) + tid];
    for (int i = tid; i < KNBR * CIN; i += 256) {
        int k = i >> 6, c = i & 63;
        int idx = nbr[(size_t)p * KNBR + k];
        sf[k * CF + c] = inp[((size_t)b * NPERB + idx) * CIN + c];
    }
    if (tid < KNBR * CADD) {
        int k = tid / CADD, c = tid - k * CADD;
        sf[k * CF + CIN + c] = addl[(size_t)p * (KNBR * CADD) + tid];
    }
    __syncthreads();
    for (int f = tid; f < KF; f += 256) {
        int c = f >> 4, m = f & 15;
        float s = 0;
#pragma unroll
        for (int k = 0; k < KNBR; k++) s += sf[k * CF + c] * sw[k * MDIM + m];
        sp[f] = s;
    }
    __syncthreads();
    const int o = tid >> 1, h = tid & 1;
    float s = 0;
    for (int f = h * (KF / 2); f < (h + 1) * (KF / 2); f++)
        s += sp[f] * lw[(size_t)o * KF + f];
    s += __shfl_xor(s, 1);
    if (h == 0) out[(size_t)p * COUT + o] = s + bias[o];
}

extern "C" void kernel_launch(void* const* d_in, const int* in_sizes, int n_in,
                              void* d_out, int out_size, void* d_ws, size_t ws_size,
                              hipStream_t stream) {
    const float* inp  = (const float*)d_in[0];
    const int*   nbr  = (const int*)d_in[1];
    // d_in[2..4] = inverse_* (backward-only, unused)
    const float* wn   = (const float*)d_in[5];
    const float* addl = (const float*)d_in[6];
    const float* lw   = (const float*)d_in[7];
    const float* bias = (const float*)d_in[8];
    float* out = (float*)d_out;

    const size_t lw_bytes = (size_t)COUT * KP * sizeof(u16);   // 278,528
    const size_t pc_bytes = (size_t)NPTS * KP * sizeof(u16);   // 174,080,000

    if (ws_size >= lw_bytes + pc_bytes) {
        u16* lwp = (u16*)d_ws;
        u16* pcw = lwp + (size_t)COUT * KP;
        prep_lw_kernel<<<(COUT * KP + 255) / 256, 256, 0, stream>>>(lw, lwp);
        pconv_kernel<<<NPTS / PPB, 256, 0, stream>>>(inp, nbr, wn, addl, pcw);
        gemm_kernel<<<NPTS / GR, 512, 0, stream>>>(pcw, lwp, bias, out);
    } else if (ws_size >= lw_bytes) {
        u16* lwp = (u16*)d_ws;
        prep_lw_kernel<<<(COUT * KP + 255) / 256, 256, 0, stream>>>(lw, lwp);
        fused_kernel<<<NPTS / PTSB, 512, 0, stream>>>(inp, nbr, wn, addl, lwp, bias, out);
    } else {
        fused_fallback_kernel<<<NPTS, 256, 0, stream>>>(inp, nbr, wn, addl, lw, bias, out);
    }
}

// Round 3
// 343.743 us; speedup vs baseline: 1.1008x; 1.1008x over previous
//
#include <hip/hip_runtime.h>
#include <stdint.h>

typedef unsigned short u16;
typedef short short8 __attribute__((ext_vector_type(8)));
typedef float floatx4 __attribute__((ext_vector_type(4)));

#define NPERB   40000
#define NPTS    80000
#define KNBR    16
#define CIN     64
#define MDIM    16
#define CADD    3
#define CF      (CIN + CADD)
#define COUT    128
#define KF      1072
#define KP      1088
#define NKT     34        // KP/32 K-steps
#define PTSB    16        // fused-fallback: points per block
#define SLAB    65        // fused-fallback: chunks per kt slab
#define GR      128       // gemm: rows per block (4 waves x 32)
#define PPB     8         // pconv: points per block (4 waves x 2)

__device__ __forceinline__ u16 f2bf(float f) {
    union { float f; unsigned int u; } v; v.f = f;
    unsigned int u = v.u;
    return (u16)((u + 0x7FFFu + ((u >> 16) & 1u)) >> 16);
}
__device__ __forceinline__ short8 pack8(floatx4 x, floatx4 y) {
    union { short8 v; u16 a[8]; } u;
    u.a[0] = f2bf(x[0]); u.a[1] = f2bf(x[1]); u.a[2] = f2bf(x[2]); u.a[3] = f2bf(x[3]);
    u.a[4] = f2bf(y[0]); u.a[5] = f2bf(y[1]); u.a[6] = f2bf(y[2]); u.a[7] = f2bf(y[3]);
    return u.v;
}
// fused-fallback swizzle (16B-chunk XOR)
__device__ __forceinline__ unsigned swz(unsigned chunk) {
    return chunk ^ ((chunk >> 3) & 7u);
}
// async global -> LDS, 16B per lane; LDS dest = uniform base + lane*16 (linear).
__device__ __forceinline__ void gload_lds16(const void* g, void* l) {
    __builtin_amdgcn_global_load_lds(
        (const __attribute__((address_space(1))) void*)g,
        (__attribute__((address_space(3))) void*)l, 16, 0, 0);
}

// Convert+pad linear_weight fp32 [128,1072] -> bf16 ws [128,1088] (zero pad).
__global__ void prep_lw_kernel(const float* __restrict__ lw, u16* __restrict__ lwp) {
    int i = blockIdx.x * 256 + threadIdx.x;
    if (i >= COUT * KP) return;
    int o = i / KP, f = i - o * KP;
    lwp[i] = (f < KF) ? f2bf(lw[(size_t)o * KF + f]) : (u16)0;
}

// ============================ SPLIT PATH ============================
// Kernel 1: pconv (UNCHANGED from r2 - ~80us vs ~50us floor; isolate its
// counters this round). One wave = 2 points; row-major bf16 pconv rows.
__device__ __forceinline__ void emit_point(
    int lane, float av, const float (&fv)[KNBR], const float* wl,
    u16* __restrict__ dst)
{
    const int em = lane & 15, ec = lane >> 4;
    float ev = 0.f;
#pragma unroll
    for (int k = 0; k < KNBR; k++)
        ev += __shfl(av, k * CADD + ec) * wl[k * MDIM + em];
    if (ec == 3) ev = 0.f;                       // channel 67 + f>=1072 pad
    dst[1024 + lane] = f2bf(ev);

    floatx4 a0 = 0, a1 = 0, a2 = 0, a3 = 0;
#pragma unroll
    for (int k = 0; k < KNBR; k++) {
        const floatx4* w4 = (const floatx4*)(wl + k * MDIM);  // uniform -> bcast
        const float fvk = fv[k];
        a0 += fvk * w4[0]; a1 += fvk * w4[1];
        a2 += fvk * w4[2]; a3 += fvk * w4[3];
    }
    *(short8*)(dst + lane * 16)     = pack8(a0, a1);   // m 0..7
    *(short8*)(dst + lane * 16 + 8) = pack8(a2, a3);   // m 8..15
}

__global__ __launch_bounds__(256) void pconv_kernel(
    const float* __restrict__ inp,   // [2,40000,64] fp32
    const int*   __restrict__ nbr,   // [2,40000,16] int32
    const float* __restrict__ wn,    // [2,40000,16,16] fp32
    const float* __restrict__ addl,  // [2,40000,16,3] fp32
    u16* __restrict__ pc)            // [80000,1088] bf16
{
    __shared__ __align__(16) float Wns[PPB * KNBR * MDIM];   // 8KB

    const int wave = threadIdx.x >> 6;
    const int lane = threadIdx.x & 63;
    const int pbase = blockIdx.x * PPB;         // 40000 % 8 == 0
    const float* inpb = inp + ((pbase >= NPERB) ? (size_t)NPERB * CIN : 0);

    const int pr0 = wave * 2;
    const int p0  = __builtin_amdgcn_readfirstlane(pbase + pr0);
    const int p1  = p0 + 1;

    float* wl0 = Wns + pr0 * (KNBR * MDIM);
    float* wl1 = wl0 + KNBR * MDIM;
    gload_lds16(wn + (size_t)p0 * (KNBR * MDIM) + lane * 4, wl0);
    gload_lds16(wn + (size_t)p1 * (KNBR * MDIM) + lane * 4, wl1);

    float av0 = (lane < KNBR * CADD) ? addl[(size_t)p0 * (KNBR * CADD) + lane] : 0.f;
    float av1 = (lane < KNBR * CADD) ? addl[(size_t)p1 * (KNBR * CADD) + lane] : 0.f;

    const int* nb0 = nbr + (size_t)p0 * KNBR;   // uniform -> s_loads
    const int* nb1 = nbr + (size_t)p1 * KNBR;
    int idx0[KNBR], idx1[KNBR];
#pragma unroll
    for (int k = 0; k < KNBR; k++) idx0[k] = nb0[k];
#pragma unroll
    for (int k = 0; k < KNBR; k++) idx1[k] = nb1[k];

    float fv0[KNBR], fv1[KNBR];
#pragma unroll
    for (int k = 0; k < KNBR; k++) fv0[k] = inpb[(size_t)idx0[k] * CIN + lane];
#pragma unroll
    for (int k = 0; k < KNBR; k++) fv1[k] = inpb[(size_t)idx1[k] * CIN + lane];

    asm volatile("s_waitcnt vmcnt(0)" ::: "memory");  // wn staging + gathers
    __builtin_amdgcn_sched_barrier(0);

    emit_point(lane, av0, fv0, wl0, pc + (size_t)p0 * KP);
    emit_point(lane, av1, fv1, wl1, pc + (size_t)p1 * KP);
}

// Kernel 2: GEMM [80000 x 1088]bf16 x [1088 x 128]bf16 -> fp32 (+bias).
// r2 post-mortem: per-kt __syncthreads drained the staging prefetch ->
// 4KB-in-flight/block -> latency-bound at 173us. r3: NO LDS, NO barriers.
// One wave owns 32 rows x all 128 cols; A loaded global->VGPR directly in
// MFMA fragment layout (16B/lane), B (278KB) from L2/L1; register
// double-buffer one kt ahead. ~10 loads in flight/wave x ~10 waves/CU
// keeps the A-stream at HBM BW; compiler inserts fine-grained vmcnt.
__global__ __launch_bounds__(256) void gemm_kernel(
    const u16* __restrict__ pc,     // [80000,1088] bf16
    const u16* __restrict__ lwp,    // [128,1088] bf16
    const float* __restrict__ bias, // [128] fp32
    float* __restrict__ out)        // [80000,128] fp32
{
    const int wave = threadIdx.x >> 6;
    const int lane = threadIdx.x & 63;
    const int r16 = lane & 15, quad = lane >> 4;
    const int row0 = blockIdx.x * GR + wave * 32;

    // A fragment addr: lane covers row (row0 + r16 [+16]), bytes quad*16 within
    // the kt-step's 64B row segment.
    const u16* pA0 = pc + (size_t)(row0 + r16) * KP + quad * 8;
    const u16* pA1 = pA0 + (size_t)16 * KP;
    // B fragment addr: n-th output col group = lwp row n*16+r16.
    const u16* pB  = lwp + (size_t)r16 * KP + quad * 8;

    floatx4 acc0[8], acc1[8];
#pragma unroll
    for (int n = 0; n < 8; n++) { acc0[n] = 0; acc1[n] = 0; }

    short8 Ac0, Ac1, Bc[8];     // current kt
    short8 An0, An1, Bn[8];     // next kt
    Ac0 = *(const short8*)pA0;
    Ac1 = *(const short8*)pA1;
#pragma unroll
    for (int n = 0; n < 8; n++)
        Bc[n] = *(const short8*)(pB + (size_t)n * 16 * KP);

    for (int kt = 0; kt + 1 < NKT; kt += 2) {
        // prefetch kt+1 (issues 10 loads; MFMAs below hide their latency)
        An0 = *(const short8*)(pA0 + (kt + 1) * 32);
        An1 = *(const short8*)(pA1 + (kt + 1) * 32);
#pragma unroll
        for (int n = 0; n < 8; n++)
            Bn[n] = *(const short8*)(pB + (size_t)n * 16 * KP + (kt + 1) * 32);
        // compute kt
#pragma unroll
        for (int n = 0; n < 8; n++) {
            acc0[n] = __builtin_amdgcn_mfma_f32_16x16x32_bf16(Ac0, Bc[n], acc0[n], 0, 0, 0);
            acc1[n] = __builtin_amdgcn_mfma_f32_16x16x32_bf16(Ac1, Bc[n], acc1[n], 0, 0, 0);
        }
        // prefetch kt+2
        if (kt + 2 < NKT) {
            Ac0 = *(const short8*)(pA0 + (kt + 2) * 32);
            Ac1 = *(const short8*)(pA1 + (kt + 2) * 32);
#pragma unroll
            for (int n = 0; n < 8; n++)
                Bc[n] = *(const short8*)(pB + (size_t)n * 16 * KP + (kt + 2) * 32);
        }
        // compute kt+1
#pragma unroll
        for (int n = 0; n < 8; n++) {
            acc0[n] = __builtin_amdgcn_mfma_f32_16x16x32_bf16(An0, Bn[n], acc0[n], 0, 0, 0);
            acc1[n] = __builtin_amdgcn_mfma_f32_16x16x32_bf16(An1, Bn[n], acc1[n], 0, 0, 0);
        }
    }

    // epilogue: D[row=quad*4+r][col=r16]; per row the wave writes all 128
    // cols (512B contiguous across the 8 n-groups) -> no write amplification.
#pragma unroll
    for (int n = 0; n < 8; n++) {
        const float bv = bias[n * 16 + r16];
#pragma unroll
        for (int r = 0; r < 4; r++) {
            size_t row = (size_t)(row0 + quad * 4 + r) * COUT;
            out[row + n * 16 + r16] = acc0[n][r] + bv;
            row = (size_t)(row0 + 16 + quad * 4 + r) * COUT;
            out[row + n * 16 + r16] = acc1[n][r] + bv;
        }
    }
}

// ===================== FUSED FALLBACK (r1 kernel) =====================
__device__ __forceinline__ void compute_point(
    int pr, int lane, float av, const float (&fv)[KNBR],
    const float* wl, u16* Apc)
{
    const int em = lane & 15, ec = lane >> 4;
    float ev = 0.f;
#pragma unroll
    for (int k = 0; k < KNBR; k++)
        ev += __shfl(av, k * CADD + ec) * wl[k * MDIM + em];
    if (ec == 3) ev = 0.f;
    {
        unsigned kt   = 32 + (lane >> 5);
        unsigned quad = (lane >> 3) & 3;
        unsigned ch   = kt * SLAB + (unsigned)pr * 4 + quad;
        Apc[swz(ch) * 8 + (lane & 7)] = f2bf(ev);
    }
    floatx4 a0 = 0, a1 = 0, a2 = 0, a3 = 0;
#pragma unroll
    for (int k = 0; k < KNBR; k++) {
        const floatx4* w4 = (const floatx4*)(wl + k * MDIM);
        const float fvk = fv[k];
        a0 += fvk * w4[0]; a1 += fvk * w4[1];
        a2 += fvk * w4[2]; a3 += fvk * w4[3];
    }
    {
        unsigned kt = lane >> 1, qb = (lane & 1) * 2;
        unsigned ch = kt * SLAB + (unsigned)pr * 4 + qb;
        *(short8*)&Apc[swz(ch) * 8]     = pack8(a0, a1);
        *(short8*)&Apc[swz(ch + 1) * 8] = pack8(a2, a3);
    }
}

__global__ __launch_bounds__(512, 6) void fused_kernel(
    const float* __restrict__ inp, const int* __restrict__ nbr,
    const float* __restrict__ wn, const float* __restrict__ addl,
    const u16* __restrict__ lwp, const float* __restrict__ bias,
    float* __restrict__ out)
{
    __shared__ __align__(16) u16   Apc[(NKT * SLAB + 8) * 8];
    __shared__ __align__(16) float Wns[PTSB * KNBR * MDIM];

    const int wave = threadIdx.x >> 6;
    const int lane = threadIdx.x & 63;
    const int pbase = blockIdx.x * PTSB;
    const float* inpb = inp + ((pbase >= NPERB) ? (size_t)NPERB * CIN : 0);

    const int pr0 = wave * 2;
    const int p0  = __builtin_amdgcn_readfirstlane(pbase + pr0);
    const int p1  = p0 + 1;

    float* wl0 = Wns + pr0 * (KNBR * MDIM);
    float* wl1 = wl0 + KNBR * MDIM;
    gload_lds16(wn + (size_t)p0 * (KNBR * MDIM) + lane * 4, wl0);
    gload_lds16(wn + (size_t)p1 * (KNBR * MDIM) + lane * 4, wl1);

    float av0 = (lane < KNBR * CADD) ? addl[(size_t)p0 * (KNBR * CADD) + lane] : 0.f;
    float av1 = (lane < KNBR * CADD) ? addl[(size_t)p1 * (KNBR * CADD) + lane] : 0.f;

    const int* nb0 = nbr + (size_t)p0 * KNBR;
    const int* nb1 = nbr + (size_t)p1 * KNBR;
    int idx0[KNBR], idx1[KNBR];
#pragma unroll
    for (int k = 0; k < KNBR; k++) idx0[k] = nb0[k];
#pragma unroll
    for (int k = 0; k < KNBR; k++) idx1[k] = nb1[k];

    float fv0[KNBR], fv1[KNBR];
#pragma unroll
    for (int k = 0; k < KNBR; k++) fv0[k] = inpb[(size_t)idx0[k] * CIN + lane];
#pragma unroll
    for (int k = 0; k < KNBR; k++) fv1[k] = inpb[(size_t)idx1[k] * CIN + lane];

    asm volatile("s_waitcnt vmcnt(0)" ::: "memory");
    __builtin_amdgcn_sched_barrier(0);

    compute_point(pr0,     lane, av0, fv0, wl0, Apc);
    compute_point(pr0 + 1, lane, av1, fv1, wl1, Apc);

    const int r16 = lane & 15, quad = lane >> 4;
    const int c0 = wave * 16;
    const u16* Bp = lwp + (size_t)(c0 + r16) * KP + quad * 8;
    const unsigned abase = (unsigned)r16 * 4 + quad;
    const float bv = bias[c0 + r16];

    __syncthreads();

    floatx4 acc = 0;
#pragma unroll 2
    for (int kt = 0; kt < NKT; kt++) {
        short8 A = *(const short8*)&Apc[swz((unsigned)kt * SLAB + abase) * 8];
        short8 B = *(const short8*)(Bp + kt * 32);
        acc = __builtin_amdgcn_mfma_f32_16x16x32_bf16(A, B, acc, 0, 0, 0);
    }

#pragma unroll
    for (int r = 0; r < 4; r++) {
        const size_t row = (size_t)(pbase + quad * 4 + r) * COUT;
        out[row + c0 + r16] = acc[r] + bv;
    }
}

// Slow last-resort fallback: all-fp32, one block per point.
__global__ __launch_bounds__(256) void fused_fallback_kernel(
    const float* __restrict__ inp, const int* __restrict__ nbr,
    const float* __restrict__ wn, const float* __restrict__ addl,
    const float* __restrict__ lw, const float* __restrict__ bias,
    float* __restrict__ out)
{
    const int p = blockIdx.x;
    const int b = p / NPERB;
    const int tid = threadIdx.x;
    __shared__ float sf[KNBR * CF];
    __shared__ float sw[KNBR * MDIM];
    __shared__ float sp[KF];

    sw[tid] = wn[(size_t)p * (KNBR * MDIM) + tid];
    for (int i = tid; i < KNBR * CIN; i += 256) {
        int k = i >> 6, c = i & 63;
        int idx = nbr[(size_t)p * KNBR + k];
        sf[k * CF + c] = inp[((size_t)b * NPERB + idx) * CIN + c];
    }
    if (tid < KNBR * CADD) {
        int k = tid / CADD, c = tid - k * CADD;
        sf[k * CF + CIN + c] = addl[(size_t)p * (KNBR * CADD) + tid];
    }
    __syncthreads();
    for (int f = tid; f < KF; f += 256) {
        int c = f >> 4, m = f & 15;
        float s = 0;
#pragma unroll
        for (int k = 0; k < KNBR; k++) s += sf[k * CF + c] * sw[k * MDIM + m];
        sp[f] = s;
    }
    __syncthreads();
    const int o = tid >> 1, h = tid & 1;
    float s = 0;
    for (int f = h * (KF / 2); f < (h + 1) * (KF / 2); f++)
        s += sp[f] * lw[(size_t)o * KF + f];
    s += __shfl_xor(s, 1);
    if (h == 0) out[(size_t)p * COUT + o] = s + bias[o];
}

extern "C" void kernel_launch(void* const* d_in, const int* in_sizes, int n_in,
                              void* d_out, int out_size, void* d_ws, size_t ws_size,
                              hipStream_t stream) {
    const float* inp  = (const float*)d_in[0];
    const int*   nbr  = (const int*)d_in[1];
    // d_in[2..4] = inverse_* (backward-only, unused)
    const float* wn   = (const float*)d_in[5];
    const float* addl = (const float*)d_in[6];
    const float* lw   = (const float*)d_in[7];
    const float* bias = (const float*)d_in[8];
    float* out = (float*)d_out;

    const size_t lw_bytes = (size_t)COUT * KP * sizeof(u16);   // 278,528
    const size_t pc_bytes = (size_t)NPTS * KP * sizeof(u16);   // 174,080,000

    if (ws_size >= lw_bytes + pc_bytes) {
        u16* lwp = (u16*)d_ws;
        u16* pcw = lwp + (size_t)COUT * KP;
        prep_lw_kernel<<<(COUT * KP + 255) / 256, 256, 0, stream>>>(lw, lwp);
        pconv_kernel<<<NPTS / PPB, 256, 0, stream>>>(inp, nbr, wn, addl, pcw);
        gemm_kernel<<<NPTS / GR, 256, 0, stream>>>(pcw, lwp, bias, out);
    } else if (ws_size >= lw_bytes) {
        u16* lwp = (u16*)d_ws;
        prep_lw_kernel<<<(COUT * KP + 255) / 256, 256, 0, stream>>>(lw, lwp);
        fused_kernel<<<NPTS / PTSB, 512, 0, stream>>>(inp, nbr, wn, addl, lwp, bias, out);
    } else {
        fused_fallback_kernel<<<NPTS, 256, 0, stream>>>(inp, nbr, wn, addl, lw, bias, out);
    }
}

// Round 4
// 340.881 us; speedup vs baseline: 1.1101x; 1.0084x over previous
//
#include <hip/hip_runtime.h>
#include <stdint.h>

typedef unsigned short u16;
typedef short short8 __attribute__((ext_vector_type(8)));
typedef float floatx4 __attribute__((ext_vector_type(4)));

#define NPERB   40000
#define NPTS    80000
#define KNBR    16
#define CIN     64
#define MDIM    16
#define CADD    3
#define CF      (CIN + CADD)
#define COUT    128
#define KF      1072
#define KP      1088
#define NKT     34        // KP/32 K-steps
#define PTSB    16        // fused-fallback: points per block
#define SLAB    65        // fused-fallback: chunks per kt slab
#define GR      128       // gemm: rows per block (4 waves x 32)
#define PPB     8         // pconv: points per block (4 waves x 2)

__device__ __forceinline__ u16 f2bf(float f) {
    union { float f; unsigned int u; } v; v.f = f;
    unsigned int u = v.u;
    return (u16)((u + 0x7FFFu + ((u >> 16) & 1u)) >> 16);
}
__device__ __forceinline__ short8 pack8(floatx4 x, floatx4 y) {
    union { short8 v; u16 a[8]; } u;
    u.a[0] = f2bf(x[0]); u.a[1] = f2bf(x[1]); u.a[2] = f2bf(x[2]); u.a[3] = f2bf(x[3]);
    u.a[4] = f2bf(y[0]); u.a[5] = f2bf(y[1]); u.a[6] = f2bf(y[2]); u.a[7] = f2bf(y[3]);
    return u.v;
}
// fused-fallback swizzle (16B-chunk XOR)
__device__ __forceinline__ unsigned swz(unsigned chunk) {
    return chunk ^ ((chunk >> 3) & 7u);
}
// async global -> LDS, 16B per lane; LDS dest = uniform base + lane*16 (linear).
__device__ __forceinline__ void gload_lds16(const void* g, void* l) {
    __builtin_amdgcn_global_load_lds(
        (const __attribute__((address_space(1))) void*)g,
        (__attribute__((address_space(3))) void*)l, 16, 0, 0);
}

// Convert+pad linear_weight fp32 [128,1072] -> bf16 ws [128,1088] (zero pad).
__global__ void prep_lw_kernel(const float* __restrict__ lw, u16* __restrict__ lwp) {
    int i = blockIdx.x * 256 + threadIdx.x;
    if (i >= COUT * KP) return;
    int o = i / KP, f = i - o * KP;
    lwp[i] = (f < KF) ? f2bf(lw[(size_t)o * KF + f]) : (u16)0;
}

// ============================ SPLIT PATH ============================
// Kernel 1: pconv (UNCHANGED - after gemm drops, this tops the profile
// and we get its isolated counters next round).
__device__ __forceinline__ void emit_point(
    int lane, float av, const float (&fv)[KNBR], const float* wl,
    u16* __restrict__ dst)
{
    const int em = lane & 15, ec = lane >> 4;
    float ev = 0.f;
#pragma unroll
    for (int k = 0; k < KNBR; k++)
        ev += __shfl(av, k * CADD + ec) * wl[k * MDIM + em];
    if (ec == 3) ev = 0.f;                       // channel 67 + f>=1072 pad
    dst[1024 + lane] = f2bf(ev);

    floatx4 a0 = 0, a1 = 0, a2 = 0, a3 = 0;
#pragma unroll
    for (int k = 0; k < KNBR; k++) {
        const floatx4* w4 = (const floatx4*)(wl + k * MDIM);  // uniform -> bcast
        const float fvk = fv[k];
        a0 += fvk * w4[0]; a1 += fvk * w4[1];
        a2 += fvk * w4[2]; a3 += fvk * w4[3];
    }
    *(short8*)(dst + lane * 16)     = pack8(a0, a1);   // m 0..7
    *(short8*)(dst + lane * 16 + 8) = pack8(a2, a3);   // m 8..15
}

__global__ __launch_bounds__(256) void pconv_kernel(
    const float* __restrict__ inp,   // [2,40000,64] fp32
    const int*   __restrict__ nbr,   // [2,40000,16] int32
    const float* __restrict__ wn,    // [2,40000,16,16] fp32
    const float* __restrict__ addl,  // [2,40000,16,3] fp32
    u16* __restrict__ pc)            // [80000,1088] bf16
{
    __shared__ __align__(16) float Wns[PPB * KNBR * MDIM];   // 8KB

    const int wave = threadIdx.x >> 6;
    const int lane = threadIdx.x & 63;
    const int pbase = blockIdx.x * PPB;         // 40000 % 8 == 0
    const float* inpb = inp + ((pbase >= NPERB) ? (size_t)NPERB * CIN : 0);

    const int pr0 = wave * 2;
    const int p0  = __builtin_amdgcn_readfirstlane(pbase + pr0);
    const int p1  = p0 + 1;

    float* wl0 = Wns + pr0 * (KNBR * MDIM);
    float* wl1 = wl0 + KNBR * MDIM;
    gload_lds16(wn + (size_t)p0 * (KNBR * MDIM) + lane * 4, wl0);
    gload_lds16(wn + (size_t)p1 * (KNBR * MDIM) + lane * 4, wl1);

    float av0 = (lane < KNBR * CADD) ? addl[(size_t)p0 * (KNBR * CADD) + lane] : 0.f;
    float av1 = (lane < KNBR * CADD) ? addl[(size_t)p1 * (KNBR * CADD) + lane] : 0.f;

    const int* nb0 = nbr + (size_t)p0 * KNBR;   // uniform -> s_loads
    const int* nb1 = nbr + (size_t)p1 * KNBR;
    int idx0[KNBR], idx1[KNBR];
#pragma unroll
    for (int k = 0; k < KNBR; k++) idx0[k] = nb0[k];
#pragma unroll
    for (int k = 0; k < KNBR; k++) idx1[k] = nb1[k];

    float fv0[KNBR], fv1[KNBR];
#pragma unroll
    for (int k = 0; k < KNBR; k++) fv0[k] = inpb[(size_t)idx0[k] * CIN + lane];
#pragma unroll
    for (int k = 0; k < KNBR; k++) fv1[k] = inpb[(size_t)idx1[k] * CIN + lane];

    asm volatile("s_waitcnt vmcnt(0)" ::: "memory");  // wn staging + gathers
    __builtin_amdgcn_sched_barrier(0);

    emit_point(lane, av0, fv0, wl0, pc + (size_t)p0 * KP);
    emit_point(lane, av1, fv1, wl1, pc + (size_t)p1 * KP);
}

// Kernel 2 (r4): GEMM [80000 x 1088]bf16 x [1088 x 128]bf16 -> fp32 (+bias).
// r3 post-mortem: reg double-buffer = depth 1 -> ~90cyc cover vs ~500cyc
// L3 latency -> 6% MfmaUtil. r4: zero-barrier counted-vmcnt pipeline.
// A: global->LDS (gload_lds16) into WAVE-PRIVATE slots, depth 3 -> no
// cross-wave dependency -> no barriers, loads stay in flight (T3/T4).
// B: register prefetch, depth 2. kt-loop fully unrolled (34 steps) so all
// slot/buffer indices are static (rule #20) and vmcnt(N) are hand-counted
// literals. Per-iter issue region = {2 A-gloads, 8 B-loads}; steady
// N = 20 (2 regions in flight); tail 18/8/0. sched_barrier(0) pins the
// regions; intra-region reorders only make waits conservative (safe).
// LDS slot layout is reader-linear (lane l reads byte l*16: conflict-free);
// staging SOURCE is lane-permuted instead (m173 pattern).
__global__ __launch_bounds__(256, 2) void gemm_kernel(
    const u16* __restrict__ pc,     // [80000,1088] bf16
    const u16* __restrict__ lwp,    // [128,1088] bf16
    const float* __restrict__ bias, // [128] fp32
    float* __restrict__ out)        // [80000,128] fp32
{
    __shared__ __align__(16) u16 As[4][4][1024];   // [wave][slot][2KB] = 32KB

    const int wave = threadIdx.x >> 6;
    const int lane = threadIdx.x & 63;
    const int r16 = lane & 15, quad = lane >> 4;
    const int row0 = blockIdx.x * GR + wave * 32;

    // staging source: lane i covers chunk (row = i&15 [+16 half1], quad = i>>4)
    // == exactly the MFMA A-fragment the reader lane i consumes.
    const u16* aS0 = pc + (size_t)(row0 + r16) * KP + quad * 8;
    const u16* aS1 = aS0 + (size_t)16 * KP;
    u16* aD = &As[wave][0][0];              // slot s base = aD + s*1024 (u16)

    // B fragment base: row n*16+r16, col kt*32+quad*8
    const u16* bB = lwp + (size_t)r16 * KP + quad * 8;

    float bv[8];
#pragma unroll
    for (int n = 0; n < 8; n++) bv[n] = bias[n * 16 + r16];
    __builtin_amdgcn_sched_barrier(0);      // pin bias loads in prologue

    floatx4 acc0[8], acc1[8];
#pragma unroll
    for (int n = 0; n < 8; n++) { acc0[n] = 0; acc1[n] = 0; }

    short8 Bq[3][8];                        // static-indexed after full unroll

#define STAGE(s) { \
    gload_lds16(aS0 + (s) * 32, aD + ((s) & 3) * 1024); \
    gload_lds16(aS1 + (s) * 32, aD + ((s) & 3) * 1024 + 512); }

#define LOADB(s) { \
    _Pragma("unroll") \
    for (int n = 0; n < 8; n++) \
        Bq[(s) % 3][n] = *(const short8*)(bB + (size_t)n * 16 * KP + (s) * 32); }

    // prologue: A depth-3, B depth-2; SBs fix the relative issue order
    // the vmcnt counting below assumes.
    STAGE(0); STAGE(1); STAGE(2);
    __builtin_amdgcn_sched_barrier(0);
    LOADB(0);
    __builtin_amdgcn_sched_barrier(0);
    LOADB(1);
    __builtin_amdgcn_sched_barrier(0);

    // N(kt) = #vm-ops issued after the last B(kt) load:
    //   iter kt-1: 2*(kt<32) + 8*(kt<33); iter kt: 2*(kt<31) + 8*(kt<32)
    //   (kt=0: B(0) in prologue, followed by B(1)=8 + iter0's 10 -> 18)
    // A(kt) is always older than B(kt), so covering B covers A.
#define STEP(kt, N) { \
    if ((kt) + 3 < NKT) STAGE((kt) + 3); \
    if ((kt) + 2 < NKT) LOADB((kt) + 2); \
    __builtin_amdgcn_sched_barrier(0); \
    asm volatile("s_waitcnt vmcnt(" #N ")"); \
    __builtin_amdgcn_sched_barrier(0); \
    short8 A0 = *(const short8*)(aD + ((kt) & 3) * 1024 + lane * 8); \
    short8 A1 = *(const short8*)(aD + ((kt) & 3) * 1024 + 512 + lane * 8); \
    asm volatile("s_waitcnt lgkmcnt(0)"); \
    __builtin_amdgcn_sched_barrier(0); \
    _Pragma("unroll") \
    for (int n = 0; n < 8; n++) { \
        acc0[n] = __builtin_amdgcn_mfma_f32_16x16x32_bf16(A0, Bq[(kt) % 3][n], acc0[n], 0, 0, 0); \
        acc1[n] = __builtin_amdgcn_mfma_f32_16x16x32_bf16(A1, Bq[(kt) % 3][n], acc1[n], 0, 0, 0); \
    } }

    STEP(0, 18)  STEP(1, 20)  STEP(2, 20)  STEP(3, 20)  STEP(4, 20)
    STEP(5, 20)  STEP(6, 20)  STEP(7, 20)  STEP(8, 20)  STEP(9, 20)
    STEP(10, 20) STEP(11, 20) STEP(12, 20) STEP(13, 20) STEP(14, 20)
    STEP(15, 20) STEP(16, 20) STEP(17, 20) STEP(18, 20) STEP(19, 20)
    STEP(20, 20) STEP(21, 20) STEP(22, 20) STEP(23, 20) STEP(24, 20)
    STEP(25, 20) STEP(26, 20) STEP(27, 20) STEP(28, 20) STEP(29, 20)
    STEP(30, 20) STEP(31, 18) STEP(32, 8)  STEP(33, 0)

#undef STEP
#undef LOADB
#undef STAGE

    // epilogue: D[row=quad*4+r][col=r16]; per row the wave writes all 128
    // cols (512B contiguous across the 8 n-groups) -> no write amplification.
#pragma unroll
    for (int n = 0; n < 8; n++) {
#pragma unroll
        for (int r = 0; r < 4; r++) {
            size_t row = (size_t)(row0 + quad * 4 + r) * COUT;
            out[row + n * 16 + r16] = acc0[n][r] + bv[n];
            row = (size_t)(row0 + 16 + quad * 4 + r) * COUT;
            out[row + n * 16 + r16] = acc1[n][r] + bv[n];
        }
    }
}

// ===================== FUSED FALLBACK (r1 kernel) =====================
__device__ __forceinline__ void compute_point(
    int pr, int lane, float av, const float (&fv)[KNBR],
    const float* wl, u16* Apc)
{
    const int em = lane & 15, ec = lane >> 4;
    float ev = 0.f;
#pragma unroll
    for (int k = 0; k < KNBR; k++)
        ev += __shfl(av, k * CADD + ec) * wl[k * MDIM + em];
    if (ec == 3) ev = 0.f;
    {
        unsigned kt   = 32 + (lane >> 5);
        unsigned quad = (lane >> 3) & 3;
        unsigned ch   = kt * SLAB + (unsigned)pr * 4 + quad;
        Apc[swz(ch) * 8 + (lane & 7)] = f2bf(ev);
    }
    floatx4 a0 = 0, a1 = 0, a2 = 0, a3 = 0;
#pragma unroll
    for (int k = 0; k < KNBR; k++) {
        const floatx4* w4 = (const floatx4*)(wl + k * MDIM);
        const float fvk = fv[k];
        a0 += fvk * w4[0]; a1 += fvk * w4[1];
        a2 += fvk * w4[2]; a3 += fvk * w4[3];
    }
    {
        unsigned kt = lane >> 1, qb = (lane & 1) * 2;
        unsigned ch = kt * SLAB + (unsigned)pr * 4 + qb;
        *(short8*)&Apc[swz(ch) * 8]     = pack8(a0, a1);
        *(short8*)&Apc[swz(ch + 1) * 8] = pack8(a2, a3);
    }
}

__global__ __launch_bounds__(512, 6) void fused_kernel(
    const float* __restrict__ inp, const int* __restrict__ nbr,
    const float* __restrict__ wn, const float* __restrict__ addl,
    const u16* __restrict__ lwp, const float* __restrict__ bias,
    float* __restrict__ out)
{
    __shared__ __align__(16) u16   Apc[(NKT * SLAB + 8) * 8];
    __shared__ __align__(16) float Wns[PTSB * KNBR * MDIM];

    const int wave = threadIdx.x >> 6;
    const int lane = threadIdx.x & 63;
    const int pbase = blockIdx.x * PTSB;
    const float* inpb = inp + ((pbase >= NPERB) ? (size_t)NPERB * CIN : 0);

    const int pr0 = wave * 2;
    const int p0  = __builtin_amdgcn_readfirstlane(pbase + pr0);
    const int p1  = p0 + 1;

    float* wl0 = Wns + pr0 * (KNBR * MDIM);
    float* wl1 = wl0 + KNBR * MDIM;
    gload_lds16(wn + (size_t)p0 * (KNBR * MDIM) + lane * 4, wl0);
    gload_lds16(wn + (size_t)p1 * (KNBR * MDIM) + lane * 4, wl1);

    float av0 = (lane < KNBR * CADD) ? addl[(size_t)p0 * (KNBR * CADD) + lane] : 0.f;
    float av1 = (lane < KNBR * CADD) ? addl[(size_t)p1 * (KNBR * CADD) + lane] : 0.f;

    const int* nb0 = nbr + (size_t)p0 * KNBR;
    const int* nb1 = nbr + (size_t)p1 * KNBR;
    int idx0[KNBR], idx1[KNBR];
#pragma unroll
    for (int k = 0; k < KNBR; k++) idx0[k] = nb0[k];
#pragma unroll
    for (int k = 0; k < KNBR; k++) idx1[k] = nb1[k];

    float fv0[KNBR], fv1[KNBR];
#pragma unroll
    for (int k = 0; k < KNBR; k++) fv0[k] = inpb[(size_t)idx0[k] * CIN + lane];
#pragma unroll
    for (int k = 0; k < KNBR; k++) fv1[k] = inpb[(size_t)idx1[k] * CIN + lane];

    asm volatile("s_waitcnt vmcnt(0)" ::: "memory");
    __builtin_amdgcn_sched_barrier(0);

    compute_point(pr0,     lane, av0, fv0, wl0, Apc);
    compute_point(pr0 + 1, lane, av1, fv1, wl1, Apc);

    const int r16 = lane & 15, quad = lane >> 4;
    const int c0 = wave * 16;
    const u16* Bp = lwp + (size_t)(c0 + r16) * KP + quad * 8;
    const unsigned abase = (unsigned)r16 * 4 + quad;
    const float bv = bias[c0 + r16];

    __syncthreads();

    floatx4 acc = 0;
#pragma unroll 2
    for (int kt = 0; kt < NKT; kt++) {
        short8 A = *(const short8*)&Apc[swz((unsigned)kt * SLAB + abase) * 8];
        short8 B = *(const short8*)(Bp + kt * 32);
        acc = __builtin_amdgcn_mfma_f32_16x16x32_bf16(A, B, acc, 0, 0, 0);
    }

#pragma unroll
    for (int r = 0; r < 4; r++) {
        const size_t row = (size_t)(pbase + quad * 4 + r) * COUT;
        out[row + c0 + r16] = acc[r] + bv;
    }
}

// Slow last-resort fallback: all-fp32, one block per point.
__global__ __launch_bounds__(256) void fused_fallback_kernel(
    const float* __restrict__ inp, const int* __restrict__ nbr,
    const float* __restrict__ wn, const float* __restrict__ addl,
    const float* __restrict__ lw, const float* __restrict__ bias,
    float* __restrict__ out)
{
    const int p = blockIdx.x;
    const int b = p / NPERB;
    const int tid = threadIdx.x;
    __shared__ float sf[KNBR * CF];
    __shared__ float sw[KNBR * MDIM];
    __shared__ float sp[KF];

    sw[tid] = wn[(size_t)p * (KNBR * MDIM) + tid];
    for (int i = tid; i < KNBR * CIN; i += 256) {
        int k = i >> 6, c = i & 63;
        int idx = nbr[(size_t)p * KNBR + k];
        sf[k * CF + c] = inp[((size_t)b * NPERB + idx) * CIN + c];
    }
    if (tid < KNBR * CADD) {
        int k = tid / CADD, c = tid - k * CADD;
        sf[k * CF + CIN + c] = addl[(size_t)p * (KNBR * CADD) + tid];
    }
    __syncthreads();
    for (int f = tid; f < KF; f += 256) {
        int c = f >> 4, m = f & 15;
        float s = 0;
#pragma unroll
        for (int k = 0; k < KNBR; k++) s += sf[k * CF + c] * sw[k * MDIM + m];
        sp[f] = s;
    }
    __syncthreads();
    const int o = tid >> 1, h = tid & 1;
    float s = 0;
    for (int f = h * (KF / 2); f < (h + 1) * (KF / 2); f++)
        s += sp[f] * lw[(size_t)o * KF + f];
    s += __shfl_xor(s, 1);
    if (h == 0) out[(size_t)p * COUT + o] = s + bias[o];
}

extern "C" void kernel_launch(void* const* d_in, const int* in_sizes, int n_in,
                              void* d_out, int out_size, void* d_ws, size_t ws_size,
                              hipStream_t stream) {
    const float* inp  = (const float*)d_in[0];
    const int*   nbr  = (const int*)d_in[1];
    // d_in[2..4] = inverse_* (backward-only, unused)
    const float* wn   = (const float*)d_in[5];
    const float* addl = (const float*)d_in[6];
    const float* lw   = (const float*)d_in[7];
    const float* bias = (const float*)d_in[8];
    float* out = (float*)d_out;

    const size_t lw_bytes = (size_t)COUT * KP * sizeof(u16);   // 278,528
    const size_t pc_bytes = (size_t)NPTS * KP * sizeof(u16);   // 174,080,000

    if (ws_size >= lw_bytes + pc_bytes) {
        u16* lwp = (u16*)d_ws;
        u16* pcw = lwp + (size_t)COUT * KP;
        prep_lw_kernel<<<(COUT * KP + 255) / 256, 256, 0, stream>>>(lw, lwp);
        pconv_kernel<<<NPTS / PPB, 256, 0, stream>>>(inp, nbr, wn, addl, pcw);
        gemm_kernel<<<NPTS / GR, 256, 0, stream>>>(pcw, lwp, bias, out);
    } else if (ws_size >= lw_bytes) {
        u16* lwp = (u16*)d_ws;
        prep_lw_kernel<<<(COUT * KP + 255) / 256, 256, 0, stream>>>(lw, lwp);
        fused_kernel<<<NPTS / PTSB, 512, 0, stream>>>(inp, nbr, wn, addl, lwp, bias, out);
    } else {
        fused_fallback_kernel<<<NPTS, 256, 0, stream>>>(inp, nbr, wn, addl, lw, bias, out);
    }
}

// Round 6
// 335.251 us; speedup vs baseline: 1.1287x; 1.0168x over previous
//
#include <hip/hip_runtime.h>
#include <stdint.h>

typedef unsigned short u16;
typedef short short8 __attribute__((ext_vector_type(8)));
typedef float floatx4 __attribute__((ext_vector_type(4)));

#define NPERB   40000
#define NPTS    80000
#define KNBR    16
#define CIN     64
#define MDIM    16
#define CADD    3
#define CF      (CIN + CADD)
#define COUT    128
#define KF      1072
#define KP      1088
#define NKT     34        // KP/32 K-steps
#define PTSB    16        // fused-fallback: points per block
#define SLAB    65        // fused-fallback: chunks per kt slab
#define GRB     64        // gemm: rows per block (2 row-halves x 32)
#define PPB     8         // pconv: points per block (4 waves x 2)

__device__ __forceinline__ u16 f2bf(float f) {
    union { float f; unsigned int u; } v; v.f = f;
    unsigned int u = v.u;
    return (u16)((u + 0x7FFFu + ((u >> 16) & 1u)) >> 16);
}
__device__ __forceinline__ short8 pack8(floatx4 x, floatx4 y) {
    union { short8 v; u16 a[8]; } u;
    u.a[0] = f2bf(x[0]); u.a[1] = f2bf(x[1]); u.a[2] = f2bf(x[2]); u.a[3] = f2bf(x[3]);
    u.a[4] = f2bf(y[0]); u.a[5] = f2bf(y[1]); u.a[6] = f2bf(y[2]); u.a[7] = f2bf(y[3]);
    return u.v;
}
// fused-fallback swizzle (16B-chunk XOR)
__device__ __forceinline__ unsigned swz(unsigned chunk) {
    return chunk ^ ((chunk >> 3) & 7u);
}
// async global -> LDS, 16B per lane; LDS dest = uniform base + lane*16 (linear).
__device__ __forceinline__ void gload_lds16(const void* g, void* l) {
    __builtin_amdgcn_global_load_lds(
        (const __attribute__((address_space(1))) void*)g,
        (__attribute__((address_space(3))) void*)l, 16, 0, 0);
}

// Convert+pad linear_weight fp32 [128,1072] -> bf16 ws [128,1088] (zero pad).
__global__ void prep_lw_kernel(const float* __restrict__ lw, u16* __restrict__ lwp) {
    int i = blockIdx.x * 256 + threadIdx.x;
    if (i >= COUT * KP) return;
    int o = i / KP, f = i - o * KP;
    lwp[i] = (f < KF) ? f2bf(lw[(size_t)o * KF + f]) : (u16)0;
}

// ============================ SPLIT PATH ============================
// Kernel 1: pconv (UNCHANGED - with gemm fixed this tops the profile and
// we get its isolated counters next round).
__device__ __forceinline__ void emit_point(
    int lane, float av, const float (&fv)[KNBR], const float* wl,
    u16* __restrict__ dst)
{
    const int em = lane & 15, ec = lane >> 4;
    float ev = 0.f;
#pragma unroll
    for (int k = 0; k < KNBR; k++)
        ev += __shfl(av, k * CADD + ec) * wl[k * MDIM + em];
    if (ec == 3) ev = 0.f;                       // channel 67 + f>=1072 pad
    dst[1024 + lane] = f2bf(ev);

    floatx4 a0 = 0, a1 = 0, a2 = 0, a3 = 0;
#pragma unroll
    for (int k = 0; k < KNBR; k++) {
        const floatx4* w4 = (const floatx4*)(wl + k * MDIM);  // uniform -> bcast
        const float fvk = fv[k];
        a0 += fvk * w4[0]; a1 += fvk * w4[1];
        a2 += fvk * w4[2]; a3 += fvk * w4[3];
    }
    *(short8*)(dst + lane * 16)     = pack8(a0, a1);   // m 0..7
    *(short8*)(dst + lane * 16 + 8) = pack8(a2, a3);   // m 8..15
}

__global__ __launch_bounds__(256) void pconv_kernel(
    const float* __restrict__ inp,   // [2,40000,64] fp32
    const int*   __restrict__ nbr,   // [2,40000,16] int32
    const float* __restrict__ wn,    // [2,40000,16,16] fp32
    const float* __restrict__ addl,  // [2,40000,16,3] fp32
    u16* __restrict__ pc)            // [80000,1088] bf16
{
    __shared__ __align__(16) float Wns[PPB * KNBR * MDIM];   // 8KB

    const int wave = threadIdx.x >> 6;
    const int lane = threadIdx.x & 63;
    const int pbase = blockIdx.x * PPB;         // 40000 % 8 == 0
    const float* inpb = inp + ((pbase >= NPERB) ? (size_t)NPERB * CIN : 0);

    const int pr0 = wave * 2;
    const int p0  = __builtin_amdgcn_readfirstlane(pbase + pr0);
    const int p1  = p0 + 1;

    float* wl0 = Wns + pr0 * (KNBR * MDIM);
    float* wl1 = wl0 + KNBR * MDIM;
    gload_lds16(wn + (size_t)p0 * (KNBR * MDIM) + lane * 4, wl0);
    gload_lds16(wn + (size_t)p1 * (KNBR * MDIM) + lane * 4, wl1);

    float av0 = (lane < KNBR * CADD) ? addl[(size_t)p0 * (KNBR * CADD) + lane] : 0.f;
    float av1 = (lane < KNBR * CADD) ? addl[(size_t)p1 * (KNBR * CADD) + lane] : 0.f;

    const int* nb0 = nbr + (size_t)p0 * KNBR;   // uniform -> s_loads
    const int* nb1 = nbr + (size_t)p1 * KNBR;
    int idx0[KNBR], idx1[KNBR];
#pragma unroll
    for (int k = 0; k < KNBR; k++) idx0[k] = nb0[k];
#pragma unroll
    for (int k = 0; k < KNBR; k++) idx1[k] = nb1[k];

    float fv0[KNBR], fv1[KNBR];
#pragma unroll
    for (int k = 0; k < KNBR; k++) fv0[k] = inpb[(size_t)idx0[k] * CIN + lane];
#pragma unroll
    for (int k = 0; k < KNBR; k++) fv1[k] = inpb[(size_t)idx1[k] * CIN + lane];

    asm volatile("s_waitcnt vmcnt(0)" ::: "memory");  // wn staging + gathers
    __builtin_amdgcn_sched_barrier(0);

    emit_point(lane, av0, fv0, wl0, pc + (size_t)p0 * KP);
    emit_point(lane, av1, fv1, wl1, pc + (size_t)p1 * KP);
}

// Kernel 2 (r5 resubmit): GEMM [80000 x 1088]bf16 x [1088 x 128]bf16.
// r4 post-mortem: Bq[3][8] (96 VGPR) + acc (64) oversubscribed the RF ->
// scratch spills -> broken vmcnt counts + serial scratch latency.
// r5: wave tile 32 rows x 64 cols. Bq[3][4]=48 VGPR, acc=32 -> ~110 total,
// no spill. Block = 4 waves (2 rowhalf x 2 colhalf) = 64x128; grid 1250.
// A: global->LDS wave-private slots (zero barriers), depth 3, 16B-chunk
// swizzle c = row*4 + (quad ^ ((row>>1)&3)) realized by pre-permuting the
// GLOBAL source (LDS dest stays linear, m104/m173) -> ds_read_b128 is
// 2-way (free). B: register prefetch depth 3 (L2-hot). Full unroll: all
// indices static, all vmcnt(N) hand-counted literals; sched_barrier(0)
// BETWEEN EVERY load group so in-order retirement matches the counts.
// Steady: wait vmcnt(14) = {B(kt),S(kt) retired; A cover 3 iters, B 2}.
__global__ __launch_bounds__(256) void gemm_kernel(
    const u16* __restrict__ pc,     // [80000,1088] bf16
    const u16* __restrict__ lwp,    // [128,1088] bf16
    const float* __restrict__ bias, // [128] fp32
    float* __restrict__ out)        // [80000,128] fp32
{
    __shared__ __align__(16) u16 As[4 * 4 * 1024];   // 4 waves x 4 slots x 2KB = 32KB

    const int wave = threadIdx.x >> 6;
    const int lane = threadIdx.x & 63;
    const int r16 = lane & 15, quad = lane >> 4;
    const int rh = wave >> 1, ch = wave & 1;
    const int row0 = blockIdx.x * GRB + rh * 32;   // wave's 32 rows
    const int cb   = ch * 64;                      // wave's col base

    // staging source (lane-permuted so linear LDS dest == swizzled layout):
    // instr j covers chunks j*64+l; chunk c holds (row=c>>2, q=(c&3)^((row>>1)&3))
    const int srow = lane >> 2;                                  // 0..15
    const int sq   = (lane & 3) ^ ((lane >> 3) & 3);
    const u16* aS0 = pc + (size_t)(row0 + srow) * KP + sq * 8;        // rows 0-15
    const u16* aS1 = pc + (size_t)(row0 + 16 + srow) * KP + sq * 8;   // rows 16-31
    u16* aD = &As[wave * 4096];            // u16 units; slot s at + s*1024

    // reader chunk offset (u16): c = r16*4 + (quad ^ ((r16>>1)&3)); A1 = +512
    const unsigned cA0 = (((unsigned)r16 << 2) | ((unsigned)quad ^ ((r16 >> 1) & 3))) << 3;

    // B fragment bases: row cb + n*16 + r16, col quad*8 (+kt*32 via imm)
    const u16* bB0 = lwp + (size_t)(cb + r16) * KP + quad * 8;
    const u16* bB1 = bB0 + (size_t)16 * KP;
    const u16* bB2 = bB0 + (size_t)32 * KP;
    const u16* bB3 = bB0 + (size_t)48 * KP;

    float bv[4];
#pragma unroll
    for (int n = 0; n < 4; n++) bv[n] = bias[cb + n * 16 + r16];
    __builtin_amdgcn_sched_barrier(0);

    floatx4 acc0[4], acc1[4];
#pragma unroll
    for (int n = 0; n < 4; n++) { acc0[n] = 0; acc1[n] = 0; }

    short8 Bq[3][4];    // static-indexed after full unroll -> stays in VGPRs

#define STAGE(s) { \
    gload_lds16(aS0 + (s) * 32, aD + ((s) & 3) * 1024); \
    gload_lds16(aS1 + (s) * 32, aD + ((s) & 3) * 1024 + 512); }

#define LOADB(t) { \
    Bq[(t) % 3][0] = *(const short8*)(bB0 + (t) * 32); \
    Bq[(t) % 3][1] = *(const short8*)(bB1 + (t) * 32); \
    Bq[(t) % 3][2] = *(const short8*)(bB2 + (t) * 32); \
    Bq[(t) % 3][3] = *(const short8*)(bB3 + (t) * 32); }

    // prologue: A depth 3, B depth 2; group fences make issue order exact.
    STAGE(0) STAGE(1) STAGE(2)
    __builtin_amdgcn_sched_barrier(0);
    LOADB(0)
    __builtin_amdgcn_sched_barrier(0);
    LOADB(1)
    __builtin_amdgcn_sched_barrier(0);

    // N(kt) = vm-ops issued after B(kt)'s group (B issued in STEP(kt-2),
    // S(kt) in STEP(kt-3), so retiring B(kt) retires S(kt) too):
    // steady = S(kt+1)2 + B(kt+1)4 + S(kt+2)2 + B(kt+2)4 + S(kt+3)2 = 14;
    // kt=0:10, 1:12, 2..30:14, 31:12, 32:6, 33:0.
#define STEP(kt, N) { \
    if ((kt) + 2 < NKT) { LOADB((kt) + 2) __builtin_amdgcn_sched_barrier(0); } \
    if ((kt) + 3 < NKT) { STAGE((kt) + 3) __builtin_amdgcn_sched_barrier(0); } \
    asm volatile("s_waitcnt vmcnt(" #N ")" ::: "memory"); \
    __builtin_amdgcn_sched_barrier(0); \
    short8 A0 = *(const short8*)(aD + ((kt) & 3) * 1024 + cA0); \
    short8 A1 = *(const short8*)(aD + ((kt) & 3) * 1024 + cA0 + 512); \
    asm volatile("s_waitcnt lgkmcnt(0)" ::: "memory"); \
    __builtin_amdgcn_sched_barrier(0); \
    _Pragma("unroll") \
    for (int n = 0; n < 4; n++) { \
        acc0[n] = __builtin_amdgcn_mfma_f32_16x16x32_bf16(A0, Bq[(kt) % 3][n], acc0[n], 0, 0, 0); \
        acc1[n] = __builtin_amdgcn_mfma_f32_16x16x32_bf16(A1, Bq[(kt) % 3][n], acc1[n], 0, 0, 0); \
    } }

    STEP(0, 10)  STEP(1, 12)  STEP(2, 14)  STEP(3, 14)  STEP(4, 14)
    STEP(5, 14)  STEP(6, 14)  STEP(7, 14)  STEP(8, 14)  STEP(9, 14)
    STEP(10, 14) STEP(11, 14) STEP(12, 14) STEP(13, 14) STEP(14, 14)
    STEP(15, 14) STEP(16, 14) STEP(17, 14) STEP(18, 14) STEP(19, 14)
    STEP(20, 14) STEP(21, 14) STEP(22, 14) STEP(23, 14) STEP(24, 14)
    STEP(25, 14) STEP(26, 14) STEP(27, 14) STEP(28, 14) STEP(29, 14)
    STEP(30, 14) STEP(31, 12) STEP(32, 6)  STEP(33, 0)

#undef STEP
#undef LOADB
#undef STAGE

    // epilogue: D[row=quad*4+r][col=r16]; per (r,half) the 4 n-stores are
    // back-to-back -> 256B/row write granule (r1 lesson: >=128B is clean).
#pragma unroll
    for (int r = 0; r < 4; r++) {
        {
            const size_t row = (size_t)(row0 + quad * 4 + r) * COUT;
#pragma unroll
            for (int n = 0; n < 4; n++)
                out[row + cb + n * 16 + r16] = acc0[n][r] + bv[n];
        }
        {
            const size_t row = (size_t)(row0 + 16 + quad * 4 + r) * COUT;
#pragma unroll
            for (int n = 0; n < 4; n++)
                out[row + cb + n * 16 + r16] = acc1[n][r] + bv[n];
        }
    }
}

// ===================== FUSED FALLBACK (r1 kernel) =====================
__device__ __forceinline__ void compute_point(
    int pr, int lane, float av, const float (&fv)[KNBR],
    const float* wl, u16* Apc)
{
    const int em = lane & 15, ec = lane >> 4;
    float ev = 0.f;
#pragma unroll
    for (int k = 0; k < KNBR; k++)
        ev += __shfl(av, k * CADD + ec) * wl[k * MDIM + em];
    if (ec == 3) ev = 0.f;
    {
        unsigned kt   = 32 + (lane >> 5);
        unsigned quad = (lane >> 3) & 3;
        unsigned ch   = kt * SLAB + (unsigned)pr * 4 + quad;
        Apc[swz(ch) * 8 + (lane & 7)] = f2bf(ev);
    }
    floatx4 a0 = 0, a1 = 0, a2 = 0, a3 = 0;
#pragma unroll
    for (int k = 0; k < KNBR; k++) {
        const floatx4* w4 = (const floatx4*)(wl + k * MDIM);
        const float fvk = fv[k];
        a0 += fvk * w4[0]; a1 += fvk * w4[1];
        a2 += fvk * w4[2]; a3 += fvk * w4[3];
    }
    {
        unsigned kt = lane >> 1, qb = (lane & 1) * 2;
        unsigned ch = kt * SLAB + (unsigned)pr * 4 + qb;
        *(short8*)&Apc[swz(ch) * 8]     = pack8(a0, a1);
        *(short8*)&Apc[swz(ch + 1) * 8] = pack8(a2, a3);
    }
}

__global__ __launch_bounds__(512, 6) void fused_kernel(
    const float* __restrict__ inp, const int* __restrict__ nbr,
    const float* __restrict__ wn, const float* __restrict__ addl,
    const u16* __restrict__ lwp, const float* __restrict__ bias,
    float* __restrict__ out)
{
    __shared__ __align__(16) u16   Apc[(NKT * SLAB + 8) * 8];
    __shared__ __align__(16) float Wns[PTSB * KNBR * MDIM];

    const int wave = threadIdx.x >> 6;
    const int lane = threadIdx.x & 63;
    const int pbase = blockIdx.x * PTSB;
    const float* inpb = inp + ((pbase >= NPERB) ? (size_t)NPERB * CIN : 0);

    const int pr0 = wave * 2;
    const int p0  = __builtin_amdgcn_readfirstlane(pbase + pr0);
    const int p1  = p0 + 1;

    float* wl0 = Wns + pr0 * (KNBR * MDIM);
    float* wl1 = wl0 + KNBR * MDIM;
    gload_lds16(wn + (size_t)p0 * (KNBR * MDIM) + lane * 4, wl0);
    gload_lds16(wn + (size_t)p1 * (KNBR * MDIM) + lane * 4, wl1);

    float av0 = (lane < KNBR * CADD) ? addl[(size_t)p0 * (KNBR * CADD) + lane] : 0.f;
    float av1 = (lane < KNBR * CADD) ? addl[(size_t)p1 * (KNBR * CADD) + lane] : 0.f;

    const int* nb0 = nbr + (size_t)p0 * KNBR;
    const int* nb1 = nbr + (size_t)p1 * KNBR;
    int idx0[KNBR], idx1[KNBR];
#pragma unroll
    for (int k = 0; k < KNBR; k++) idx0[k] = nb0[k];
#pragma unroll
    for (int k = 0; k < KNBR; k++) idx1[k] = nb1[k];

    float fv0[KNBR], fv1[KNBR];
#pragma unroll
    for (int k = 0; k < KNBR; k++) fv0[k] = inpb[(size_t)idx0[k] * CIN + lane];
#pragma unroll
    for (int k = 0; k < KNBR; k++) fv1[k] = inpb[(size_t)idx1[k] * CIN + lane];

    asm volatile("s_waitcnt vmcnt(0)" ::: "memory");
    __builtin_amdgcn_sched_barrier(0);

    compute_point(pr0,     lane, av0, fv0, wl0, Apc);
    compute_point(pr0 + 1, lane, av1, fv1, wl1, Apc);

    const int r16 = lane & 15, quad = lane >> 4;
    const int c0 = wave * 16;
    const u16* Bp = lwp + (size_t)(c0 + r16) * KP + quad * 8;
    const unsigned abase = (unsigned)r16 * 4 + quad;
    const float bv = bias[c0 + r16];

    __syncthreads();

    floatx4 acc = 0;
#pragma unroll 2
    for (int kt = 0; kt < NKT; kt++) {
        short8 A = *(const short8*)&Apc[swz((unsigned)kt * SLAB + abase) * 8];
        short8 B = *(const short8*)(Bp + kt * 32);
        acc = __builtin_amdgcn_mfma_f32_16x16x32_bf16(A, B, acc, 0, 0, 0);
    }

#pragma unroll
    for (int r = 0; r < 4; r++) {
        const size_t row = (size_t)(pbase + quad * 4 + r) * COUT;
        out[row + c0 + r16] = acc[r] + bv;
    }
}

// Slow last-resort fallback: all-fp32, one block per point.
__global__ __launch_bounds__(256) void fused_fallback_kernel(
    const float* __restrict__ inp, const int* __restrict__ nbr,
    const float* __restrict__ wn, const float* __restrict__ addl,
    const float* __restrict__ lw, const float* __restrict__ bias,
    float* __restrict__ out)
{
    const int p = blockIdx.x;
    const int b = p / NPERB;
    const int tid = threadIdx.x;
    __shared__ float sf[KNBR * CF];
    __shared__ float sw[KNBR * MDIM];
    __shared__ float sp[KF];

    sw[tid] = wn[(size_t)p * (KNBR * MDIM) + tid];
    for (int i = tid; i < KNBR * CIN; i += 256) {
        int k = i >> 6, c = i & 63;
        int idx = nbr[(size_t)p * KNBR + k];
        sf[k * CF + c] = inp[((size_t)b * NPERB + idx) * CIN + c];
    }
    if (tid < KNBR * CADD) {
        int k = tid / CADD, c = tid - k * CADD;
        sf[k * CF + CIN + c] = addl[(size_t)p * (KNBR * CADD) + tid];
    }
    __syncthreads();
    for (int f = tid; f < KF; f += 256) {
        int c = f >> 4, m = f & 15;
        float s = 0;
#pragma unroll
        for (int k = 0; k < KNBR; k++) s += sf[k * CF + c] * sw[k * MDIM + m];
        sp[f] = s;
    }
    __syncthreads();
    const int o = tid >> 1, h = tid & 1;
    float s = 0;
    for (int f = h * (KF / 2); f < (h + 1) * (KF / 2); f++)
        s += sp[f] * lw[(size_t)o * KF + f];
    s += __shfl_xor(s, 1);
    if (h == 0) out[(size_t)p * COUT + o] = s + bias[o];
}

extern "C" void kernel_launch(void* const* d_in, const int* in_sizes, int n_in,
                              void* d_out, int out_size, void* d_ws, size_t ws_size,
                              hipStream_t stream) {
    const float* inp  = (const float*)d_in[0];
    const int*   nbr  = (const int*)d_in[1];
    // d_in[2..4] = inverse_* (backward-only, unused)
    const float* wn   = (const float*)d_in[5];
    const float* addl = (const float*)d_in[6];
    const float* lw   = (const float*)d_in[7];
    const float* bias = (const float*)d_in[8];
    float* out = (float*)d_out;

    const size_t lw_bytes = (size_t)COUT * KP * sizeof(u16);   // 278,528
    const size_t pc_bytes = (size_t)NPTS * KP * sizeof(u16);   // 174,080,000

    if (ws_size >= lw_bytes + pc_bytes) {
        u16* lwp = (u16*)d_ws;
        u16* pcw = lwp + (size_t)COUT * KP;
        prep_lw_kernel<<<(COUT * KP + 255) / 256, 256, 0, stream>>>(lw, lwp);
        pconv_kernel<<<NPTS / PPB, 256, 0, stream>>>(inp, nbr, wn, addl, pcw);
        gemm_kernel<<<NPTS / GRB, 256, 0, stream>>>(pcw, lwp, bias, out);
    } else if (ws_size >= lw_bytes) {
        u16* lwp = (u16*)d_ws;
        prep_lw_kernel<<<(COUT * KP + 255) / 256, 256, 0, stream>>>(lw, lwp);
        fused_kernel<<<NPTS / PTSB, 512, 0, stream>>>(inp, nbr, wn, addl, lwp, bias, out);
    } else {
        fused_fallback_kernel<<<NPTS, 256, 0, stream>>>(inp, nbr, wn, addl, lw, bias, out);
    }
}